// Round 1
// baseline (851.962 us; speedup 1.0000x reference)
//
#include <hip/hip_runtime.h>
#include <hip/hip_bf16.h>

// Problem constants
#define B_  16
#define C_  512
#define H_  64
#define W_  64
#define R_  64
#define PLANE (H_*W_)      // 4096
#define POS_  (C_ + W_ + H_)  // 640

// ---------------------------------------------------------------------------
// Kernel 1: fused global reductions over x.
//   gc[b*512+c] = sum over (h,w) of x[b,c,:,:]
//   gw[b*64+w]  = sum over (c,h)
//   gh[b*64+h]  = sum over (c,w)
// One block per (b,c) plane; 256 threads = 4 row-quarters x 64 w-lanes.
// ---------------------------------------------------------------------------
__global__ __launch_bounds__(256) void k_reduce(const float* __restrict__ x,
                                                float* __restrict__ gc,
                                                float* __restrict__ gw,
                                                float* __restrict__ gh)
{
    const int bc = blockIdx.x;            // b*512 + c
    const int b  = bc >> 9;
    const int tid = threadIdx.x;
    const int wl = tid & 63;
    const int q  = tid >> 6;              // wave id = row quarter (h = q*16 .. q*16+15)

    const float* xp = x + (size_t)bc * PLANE + (q * 16) * W_ + wl;

    float rows[16];
    float colsum = 0.f;
#pragma unroll
    for (int rr = 0; rr < 16; ++rr) {
        rows[rr] = xp[rr * W_];
        colsum += rows[rr];
    }

    // row sums (reduce over the 64 w-lanes of this wave), one atomic per row
#pragma unroll
    for (int rr = 0; rr < 16; ++rr) {
        float v = rows[rr];
        v += __shfl_xor(v, 1, 64);
        v += __shfl_xor(v, 2, 64);
        v += __shfl_xor(v, 4, 64);
        v += __shfl_xor(v, 8, 64);
        v += __shfl_xor(v, 16, 64);
        v += __shfl_xor(v, 32, 64);
        if (wl == 0) atomicAdd(gh + b * H_ + q * 16 + rr, v);
    }

    // column sums across the 4 waves
    __shared__ float colpart[4][64];
    colpart[q][wl] = colsum;
    __syncthreads();
    if (tid < 64) {
        float col = colpart[0][tid] + colpart[1][tid] + colpart[2][tid] + colpart[3][tid];
        atomicAdd(gw + b * W_ + tid, col);
        float tot = col;
        tot += __shfl_xor(tot, 1, 64);
        tot += __shfl_xor(tot, 2, 64);
        tot += __shfl_xor(tot, 4, 64);
        tot += __shfl_xor(tot, 8, 64);
        tot += __shfl_xor(tot, 16, 64);
        tot += __shfl_xor(tot, 32, 64);
        if (tid == 0) gc[bc] = tot;   // plane sum (divide later)
    }
}

// ---------------------------------------------------------------------------
// Kernel 2: conv1d (cross-correlation, pad 1) + PReLU for the three branches.
// Outputs stored r-contiguous:
//   Ar[b][c][r] = c_out[b,r,c],  Ww[b][w][r] = w_out[b,r,w],  Hh[b][h][r] = h_out[b,r,h]
// ---------------------------------------------------------------------------
__global__ __launch_bounds__(256) void k_prep(const float* __restrict__ gc,
                                              const float* __restrict__ gw,
                                              const float* __restrict__ gh,
                                              const float* __restrict__ w_c,
                                              const float* __restrict__ a_c,
                                              const float* __restrict__ w_w,
                                              const float* __restrict__ a_w,
                                              const float* __restrict__ w_h,
                                              const float* __restrict__ a_h,
                                              float* __restrict__ Ar,
                                              float* __restrict__ Ww,
                                              float* __restrict__ Hh)
{
    const int o = blockIdx.x * 256 + threadIdx.x;
    if (o >= B_ * POS_ * R_) return;
    const int r   = o & 63;
    const int pos = (o >> 6) % POS_;
    const int b   = o / (POS_ * R_);

    if (pos < C_) {
        const float sc = 1.f / (float)PLANE;
        const int c = pos;
        float g0 = (c > 0)      ? gc[b * C_ + c - 1] * sc : 0.f;
        float g1 =                gc[b * C_ + c]     * sc;
        float g2 = (c < C_ - 1) ? gc[b * C_ + c + 1] * sc : 0.f;
        float v = fmaf(g0, w_c[r * 3 + 0], fmaf(g1, w_c[r * 3 + 1], g2 * w_c[r * 3 + 2]));
        v = (v >= 0.f) ? v : a_c[0] * v;
        Ar[((size_t)b * C_ + c) * R_ + r] = v;
    } else if (pos < C_ + W_) {
        const float sc = 1.f / (float)(C_ * H_);
        const int w = pos - C_;
        float g0 = (w > 0)      ? gw[b * W_ + w - 1] * sc : 0.f;
        float g1 =                gw[b * W_ + w]     * sc;
        float g2 = (w < W_ - 1) ? gw[b * W_ + w + 1] * sc : 0.f;
        float v = fmaf(g0, w_w[r * 3 + 0], fmaf(g1, w_w[r * 3 + 1], g2 * w_w[r * 3 + 2]));
        v = (v >= 0.f) ? v : a_w[0] * v;
        Ww[((size_t)b * W_ + w) * R_ + r] = v;
    } else {
        const float sc = 1.f / (float)(C_ * W_);
        const int hh = pos - C_ - W_;
        float g0 = (hh > 0)      ? gh[b * H_ + hh - 1] * sc : 0.f;
        float g1 =                 gh[b * H_ + hh]     * sc;
        float g2 = (hh < H_ - 1) ? gh[b * H_ + hh + 1] * sc : 0.f;
        float v = fmaf(g0, w_h[r * 3 + 0], fmaf(g1, w_h[r * 3 + 1], g2 * w_h[r * 3 + 2]));
        v = (v >= 0.f) ? v : a_h[0] * v;
        Hh[((size_t)b * H_ + hh) * R_ + r] = v;
    }
}

// ---------------------------------------------------------------------------
// Kernel 3: fused cp-GEMM + softmax(C) + conv3d residual + output.
// Block = (b,h): 512 threads = 64 w-lanes x 8 channel-group waves (64 ch each).
// ---------------------------------------------------------------------------
__device__ __forceinline__ void loadplane(float (&P)[9], const float* __restrict__ xb,
                                          int cc, int h, int wl,
                                          bool hvm, bool hvp, bool wvm, bool wvp)
{
    if (cc >= 0 && cc < C_) {
        const float* xp = xb + (size_t)cc * PLANE + h * W_ + wl;
        P[0] = (hvm && wvm) ? xp[-65] : 0.f;
        P[1] = (hvm)        ? xp[-64] : 0.f;
        P[2] = (hvm && wvp) ? xp[-63] : 0.f;
        P[3] = (wvm)        ? xp[-1]  : 0.f;
        P[4] =                xp[0];
        P[5] = (wvp)        ? xp[1]   : 0.f;
        P[6] = (hvp && wvm) ? xp[63]  : 0.f;
        P[7] = (hvp)        ? xp[64]  : 0.f;
        P[8] = (hvp && wvp) ? xp[65]  : 0.f;
    } else {
#pragma unroll
        for (int j = 0; j < 9; ++j) P[j] = 0.f;
    }
}

// One channel step: prefetch plane c+1 into PC, cp dot, conv3d from PA/PB/PC,
// exp + store t. Static register rotation via the 3-step caller pattern.
#define STEP(PA, PB, PC)                                                        \
    do {                                                                        \
        const int c = c0 + i;                                                   \
        loadplane(PC, xb, c + 1, h, wl, hvm, hvp, wvm, wvp);                    \
        const int cu = __builtin_amdgcn_readfirstlane(b * C_ + c);              \
        const float4* Ap = (const float4*)(Ar + (size_t)cu * R_);               \
        float a0 = 0.f, a1 = 0.f, a2 = 0.f, a3 = 0.f;                           \
        _Pragma("unroll")                                                       \
        for (int r4 = 0; r4 < 16; ++r4) {                                       \
            float4 av = Ap[r4];                                                 \
            a0 = fmaf(av.x, wv[r4].x, a0);                                      \
            a1 = fmaf(av.y, wv[r4].y, a1);                                      \
            a2 = fmaf(av.z, wv[r4].z, a2);                                      \
            a3 = fmaf(av.w, wv[r4].w, a3);                                      \
        }                                                                       \
        const float cp = (a0 + a1) + (a2 + a3);                                 \
        float ra = 0.f, rb = 0.f, rc = 0.f;                                     \
        _Pragma("unroll")                                                       \
        for (int j = 0; j < 9; ++j) {                                           \
            ra = fmaf(PA[j], w3[j],      ra);                                   \
            rb = fmaf(PB[j], w3[9 + j],  rb);                                   \
            rc = fmaf(PC[j], w3[18 + j], rc);                                   \
        }                                                                       \
        const float res = (ra + rb) + rc;                                       \
        const float e = __expf(cp);                                             \
        Ssum += e;                                                              \
        t_lds[c][wl] = (_Float16)(res * e);                                     \
        ++i;                                                                    \
    } while (0)

__global__ __launch_bounds__(512) void k_main(const float* __restrict__ x,
                                              const float* __restrict__ Ar,
                                              const float* __restrict__ Hh,
                                              const float* __restrict__ Ww,
                                              const float* __restrict__ w3d,
                                              float* __restrict__ out)
{
    __shared__ _Float16 t_lds[C_][64];   // 64 KiB: t = res*exp(cp)
    __shared__ float    sred[8][64];     // cross-wave softmax-denominator partials

    const int bh = blockIdx.x;
    const int b  = bh >> 6;
    const int h  = bh & 63;
    const int tid = threadIdx.x;
    const int wl  = tid & 63;
    const int cg  = tid >> 6;            // wave id: channel group
    const int c0  = cg * 64;

    const bool hvm = (h > 0), hvp = (h < H_ - 1);
    const bool wvm = (wl > 0), wvp = (wl < W_ - 1);

    const float* xb = x + (size_t)b * C_ * PLANE;

    // conv3d weights (uniform -> SGPRs)
    float w3[27];
#pragma unroll
    for (int j = 0; j < 27; ++j) w3[j] = w3d[j];

    // wv[r] = h_out[b,r,h] * w_out[b,r,w]
    float4 wv[16];
    {
        const float4* Hp = (const float4*)(Hh + ((size_t)b * H_ + h) * R_);
        const float4* Wp = (const float4*)(Ww + ((size_t)b * W_ + wl) * R_);
#pragma unroll
        for (int r4 = 0; r4 < 16; ++r4) {
            float4 hv = Hp[r4];
            float4 wq = Wp[r4];
            wv[r4] = make_float4(hv.x * wq.x, hv.y * wq.y, hv.z * wq.z, hv.w * wq.w);
        }
    }

    float PA[9], PB[9], PC[9];
    loadplane(PA, xb, c0 - 1, h, wl, hvm, hvp, wvm, wvp);
    loadplane(PB, xb, c0,     h, wl, hvm, hvp, wvm, wvp);

    float Ssum = 0.f;
    int i = 0;
#pragma unroll 1
    for (int k = 0; k < 21; ++k) {       // 63 steps, rotation period 3
        STEP(PA, PB, PC);
        STEP(PB, PC, PA);
        STEP(PC, PA, PB);
    }
    STEP(PA, PB, PC);                    // step 64 (i = 63)

    // softmax denominator per w-lane across all 8 waves
    sred[cg][wl] = Ssum;
    __syncthreads();
    float Stot = 0.f;
#pragma unroll
    for (int g = 0; g < 8; ++g) Stot += sred[g][wl];
    const float rS = 1.f / Stot;

    // out[b,c,h,w] = t * rS + x
    const float* xp2 = xb + (size_t)c0 * PLANE + h * W_ + wl;
    float* op = out + (size_t)b * C_ * PLANE + (size_t)c0 * PLANE + h * W_ + wl;
#pragma unroll 4
    for (int i2 = 0; i2 < 64; ++i2) {
        const int c = c0 + i2;
        float t = (float)t_lds[c][wl];
        *op = fmaf(t, rS, *xp2);
        op  += PLANE;
        xp2 += PLANE;
    }
}

// ---------------------------------------------------------------------------
extern "C" void kernel_launch(void* const* d_in, const int* in_sizes, int n_in,
                              void* d_out, int out_size, void* d_ws, size_t ws_size,
                              hipStream_t stream)
{
    (void)in_sizes; (void)n_in; (void)out_size; (void)ws_size;
    const float* x   = (const float*)d_in[0];
    const float* w_c = (const float*)d_in[1];
    const float* a_c = (const float*)d_in[2];
    const float* w_w = (const float*)d_in[3];
    const float* a_w = (const float*)d_in[4];
    const float* w_h = (const float*)d_in[5];
    const float* a_h = (const float*)d_in[6];
    const float* w3d = (const float*)d_in[7];
    float* out = (float*)d_out;

    float* ws = (float*)d_ws;
    float* gc = ws;                       // B*C   = 8192
    float* gw = gc + B_ * C_;             // B*W   = 1024
    float* gh = gw + B_ * W_;             // B*H   = 1024
    float* Ar = gh + B_ * H_;             // B*C*R = 524288
    float* Ww = Ar + (size_t)B_ * C_ * R_; // B*W*R = 65536
    float* Hh = Ww + (size_t)B_ * W_ * R_; // B*H*R = 65536

    // zero the accumulators (gc/gw/gh) — ws is poisoned 0xAA by the harness
    hipMemsetAsync(d_ws, 0, (size_t)(B_ * C_ + B_ * W_ + B_ * H_) * sizeof(float), stream);

    k_reduce<<<B_ * C_, 256, 0, stream>>>(x, gc, gw, gh);
    k_prep<<<(B_ * POS_ * R_ + 255) / 256, 256, 0, stream>>>(gc, gw, gh,
                                                             w_c, a_c, w_w, a_w, w_h, a_h,
                                                             Ar, Ww, Hh);
    k_main<<<B_ * H_, 512, 0, stream>>>(x, Ar, Hh, Ww, w3d, out);
}

// Round 2
// 548.132 us; speedup vs baseline: 1.5543x; 1.5543x over previous
//
#include <hip/hip_runtime.h>
#include <hip/hip_bf16.h>

// Problem constants
#define B_  16
#define C_  512
#define H_  64
#define W_  64
#define R_  64
#define PLANE (H_*W_)         // 4096

// ---------------------------------------------------------------------------
// Stage 1 reduction: NO atomics. Block = (b, group of 8 planes). 256 threads.
// Each thread owns fixed w-columns (tid&15 -> cols 4*(tid&15)..+3) and fixed
// h-rows ((tid>>4)+16k). Emits:
//   gc[b*C+c]        plane sums (owned exclusively -> direct store)
//   pw[bid*64 + w]   per-block gw partials
//   ph[bid*64 + h]   per-block gh partials
// ---------------------------------------------------------------------------
__global__ __launch_bounds__(256) void k_part(const float* __restrict__ x,
                                              float* __restrict__ gc,
                                              float* __restrict__ pw,
                                              float* __restrict__ ph)
{
    const int bid = blockIdx.x;          // b*64 + blk
    const int b   = bid >> 6;
    const int blk = bid & 63;
    const int tid = threadIdx.x;

    const float4* xp = (const float4*)(x + ((size_t)b * C_ + (size_t)blk * 8) * PLANE);

    float4 gwacc = make_float4(0.f, 0.f, 0.f, 0.f);
    float  ghacc[4] = {0.f, 0.f, 0.f, 0.f};
    float  gcp[8];

#pragma unroll
    for (int p = 0; p < 8; ++p) {
        const int base = p * 1024;       // 1024 float4 per plane
        float psum = 0.f;
#pragma unroll
        for (int k = 0; k < 4; ++k) {
            float4 v = xp[base + tid + 256 * k];
            gwacc.x += v.x; gwacc.y += v.y; gwacc.z += v.z; gwacc.w += v.w;
            float s = (v.x + v.y) + (v.z + v.w);
            ghacc[k] += s;               // h = (tid>>4) + 16k, same for all planes
            psum += s;
        }
        gcp[p] = psum;
    }

    // per-plane totals: wave butterfly then cross-wave LDS
#pragma unroll
    for (int p = 0; p < 8; ++p) {
        float v = gcp[p];
        v += __shfl_xor(v, 1, 64);
        v += __shfl_xor(v, 2, 64);
        v += __shfl_xor(v, 4, 64);
        v += __shfl_xor(v, 8, 64);
        v += __shfl_xor(v, 16, 64);
        v += __shfl_xor(v, 32, 64);
        gcp[p] = v;
    }

    __shared__ float  gcs_s[4][8];
    __shared__ float4 wpart[16][17];     // padded
    __shared__ float  hpart[64][17];     // padded

    const int wv = tid >> 6;
    const int wl = tid & 63;
    if (wl == 0) {
#pragma unroll
        for (int p = 0; p < 8; ++p) gcs_s[wv][p] = gcp[p];
    }
    wpart[tid >> 4][tid & 15] = gwacc;
#pragma unroll
    for (int k = 0; k < 4; ++k) hpart[(tid >> 4) + 16 * k][tid & 15] = ghacc[k];
    __syncthreads();

    if (tid < 8) {
        gc[b * C_ + blk * 8 + tid] =
            gcs_s[0][tid] + gcs_s[1][tid] + gcs_s[2][tid] + gcs_s[3][tid];
    }
    if (tid < 16) {
        float4 s = make_float4(0.f, 0.f, 0.f, 0.f);
#pragma unroll
        for (int g = 0; g < 16; ++g) {
            float4 t = wpart[g][tid];
            s.x += t.x; s.y += t.y; s.z += t.z; s.w += t.w;
        }
        ((float4*)(pw + (size_t)bid * 64))[tid] = s;   // cols 4*tid..4*tid+3
    }
    if (tid < 64) {
        float s = 0.f;
#pragma unroll
        for (int j = 0; j < 16; ++j) s += hpart[tid][j];
        ph[(size_t)bid * 64 + tid] = s;
    }
}

// ---------------------------------------------------------------------------
// Stage 2 + branch prep. One block per b (16 blocks, 256 threads).
// Reduces pw/ph partials, then conv1d + PReLU for all three branches.
//   Ar[b][c][r] = c_out[b,r,c], Ww[b][w][r] = w_out[b,r,w], Hh[b][h][r] = h_out[b,r,h]
// ---------------------------------------------------------------------------
__global__ __launch_bounds__(256) void k_finish(const float* __restrict__ gc,
                                                const float* __restrict__ pw,
                                                const float* __restrict__ ph,
                                                const float* __restrict__ w_c,
                                                const float* __restrict__ a_c,
                                                const float* __restrict__ w_w,
                                                const float* __restrict__ a_w,
                                                const float* __restrict__ w_h,
                                                const float* __restrict__ a_h,
                                                float* __restrict__ Ar,
                                                float* __restrict__ Ww,
                                                float* __restrict__ Hh)
{
    const int b   = blockIdx.x;
    const int tid = threadIdx.x;
    const int w   = tid & 63;
    const int q   = tid >> 6;

    __shared__ float redw[4][64], redh[4][64];
    __shared__ float gws[64], ghs[64];
    __shared__ float gcs[C_ + 2];

    float sw = 0.f, sh = 0.f;
#pragma unroll
    for (int j = 0; j < 16; ++j) {
        sw += pw[((size_t)b * 64 + q * 16 + j) * 64 + w];
        sh += ph[((size_t)b * 64 + q * 16 + j) * 64 + w];
    }
    redw[q][w] = sw;
    redh[q][w] = sh;
    for (int i = tid; i < C_; i += 256) gcs[1 + i] = gc[b * C_ + i];
    if (tid == 0) { gcs[0] = 0.f; gcs[C_ + 1] = 0.f; }
    __syncthreads();
    if (tid < 64) {
        gws[tid] = redw[0][tid] + redw[1][tid] + redw[2][tid] + redw[3][tid];
        ghs[tid] = redh[0][tid] + redh[1][tid] + redh[2][tid] + redh[3][tid];
    }
    __syncthreads();

    const int r = tid & 63;
    // ---- channel branch: 512*64 outputs
    {
        const float k0 = w_c[r * 3], k1 = w_c[r * 3 + 1], k2 = w_c[r * 3 + 2];
        const float al = a_c[0];
        const float sc = 1.f / (float)PLANE;
        for (int jj = 0; jj < 128; ++jj) {
            const int c = (tid >> 6) + 4 * jj;
            float v = fmaf(gcs[c] * sc, k0,
                      fmaf(gcs[c + 1] * sc, k1, gcs[c + 2] * sc * k2));
            v = (v >= 0.f) ? v : al * v;
            Ar[((size_t)b * C_ + c) * R_ + r] = v;
        }
    }
    // ---- width branch: 64*64 outputs
    {
        const float k0 = w_w[r * 3], k1 = w_w[r * 3 + 1], k2 = w_w[r * 3 + 2];
        const float al = a_w[0];
        const float sc = 1.f / (float)(C_ * H_);
        for (int jj = 0; jj < 16; ++jj) {
            const int wp = (tid >> 6) + 4 * jj;
            float g0 = (wp > 0)  ? gws[wp - 1] : 0.f;
            float g1 =             gws[wp];
            float g2 = (wp < 63) ? gws[wp + 1] : 0.f;
            float v = fmaf(g0 * sc, k0, fmaf(g1 * sc, k1, g2 * sc * k2));
            v = (v >= 0.f) ? v : al * v;
            Ww[((size_t)b * W_ + wp) * R_ + r] = v;
        }
    }
    // ---- height branch: 64*64 outputs
    {
        const float k0 = w_h[r * 3], k1 = w_h[r * 3 + 1], k2 = w_h[r * 3 + 2];
        const float al = a_h[0];
        const float sc = 1.f / (float)(C_ * W_);
        for (int jj = 0; jj < 16; ++jj) {
            const int hp = (tid >> 6) + 4 * jj;
            float g0 = (hp > 0)  ? ghs[hp - 1] : 0.f;
            float g1 =             ghs[hp];
            float g2 = (hp < 63) ? ghs[hp + 1] : 0.f;
            float v = fmaf(g0 * sc, k0, fmaf(g1 * sc, k1, g2 * sc * k2));
            v = (v >= 0.f) ? v : al * v;
            Hh[((size_t)b * H_ + hp) * R_ + r] = v;
        }
    }
}

// ---------------------------------------------------------------------------
// Kernel 3: fused cp-GEMM + softmax(C) + conv3d residual + output.
// Block = (b,h) via XCD swizzle: 512 threads = 64 w-lanes x 8 channel waves.
// Plane rows loaded once per channel (3 loads); w-neighbors via shfl.
// ---------------------------------------------------------------------------
#define STEP(PA, PB, PC)                                                        \
    do {                                                                        \
        const int c  = c0 + i;                                                  \
        const int cc = c + 1;                                                   \
        float vm = 0.f, v0 = 0.f, vp = 0.f;                                     \
        if (cc < C_) {                                                          \
            const float* xp = xb + (size_t)cc * PLANE + hw;                     \
            vm = hvm ? xp[-64] : 0.f;                                           \
            v0 = xp[0];                                                         \
            vp = hvp ? xp[64] : 0.f;                                            \
        }                                                                       \
        const int cu = __builtin_amdgcn_readfirstlane(bC + c);                  \
        const float4* Ap = (const float4*)(Ar + (size_t)cu * R_);               \
        float a0 = 0.f, a1 = 0.f, a2 = 0.f, a3 = 0.f;                           \
        _Pragma("unroll")                                                       \
        for (int r4 = 0; r4 < 16; ++r4) {                                       \
            float4 av = Ap[r4];                                                 \
            a0 = fmaf(av.x, wv[r4].x, a0);                                      \
            a1 = fmaf(av.y, wv[r4].y, a1);                                      \
            a2 = fmaf(av.z, wv[r4].z, a2);                                      \
            a3 = fmaf(av.w, wv[r4].w, a3);                                      \
        }                                                                       \
        const float cp = (a0 + a1) + (a2 + a3);                                 \
        /* finish plane cc: w-neighbors via cross-lane */                       \
        {                                                                       \
            float um = __shfl_up(vm, 1, 64),  dm = __shfl_down(vm, 1, 64);      \
            float u0 = __shfl_up(v0, 1, 64),  d0 = __shfl_down(v0, 1, 64);      \
            float up = __shfl_up(vp, 1, 64),  dp = __shfl_down(vp, 1, 64);      \
            PC[0] = wvm ? um : 0.f;  PC[1] = vm;  PC[2] = wvp ? dm : 0.f;       \
            PC[3] = wvm ? u0 : 0.f;  PC[4] = v0;  PC[5] = wvp ? d0 : 0.f;       \
            PC[6] = wvm ? up : 0.f;  PC[7] = vp;  PC[8] = wvp ? dp : 0.f;       \
        }                                                                       \
        float ra = 0.f, rb = 0.f, rc = 0.f;                                     \
        _Pragma("unroll")                                                       \
        for (int j = 0; j < 9; ++j) {                                           \
            ra = fmaf(PA[j], w3[j],      ra);                                   \
            rb = fmaf(PB[j], w3[9 + j],  rb);                                   \
            rc = fmaf(PC[j], w3[18 + j], rc);                                   \
        }                                                                       \
        const float res = (ra + rb) + rc;                                       \
        const float e = __expf(cp);                                             \
        Ssum += e;                                                              \
        t_lds[c][wl] = (_Float16)(res * e);                                     \
        ++i;                                                                    \
    } while (0)

__device__ __forceinline__ void ldplane(float (&P)[9], const float* __restrict__ xb,
                                        int cc, int hw, bool hvm, bool hvp,
                                        bool wvm, bool wvp)
{
    float vm = 0.f, v0 = 0.f, vp = 0.f;
    if (cc >= 0 && cc < C_) {
        const float* xp = xb + (size_t)cc * PLANE + hw;
        vm = hvm ? xp[-64] : 0.f;
        v0 = xp[0];
        vp = hvp ? xp[64] : 0.f;
    }
    float um = __shfl_up(vm, 1, 64),  dm = __shfl_down(vm, 1, 64);
    float u0 = __shfl_up(v0, 1, 64),  d0 = __shfl_down(v0, 1, 64);
    float up = __shfl_up(vp, 1, 64),  dp = __shfl_down(vp, 1, 64);
    P[0] = wvm ? um : 0.f;  P[1] = vm;  P[2] = wvp ? dm : 0.f;
    P[3] = wvm ? u0 : 0.f;  P[4] = v0;  P[5] = wvp ? d0 : 0.f;
    P[6] = wvm ? up : 0.f;  P[7] = vp;  P[8] = wvp ? dp : 0.f;
}

__global__ __launch_bounds__(512) void k_main(const float* __restrict__ x,
                                              const float* __restrict__ Ar,
                                              const float* __restrict__ Hh,
                                              const float* __restrict__ Ww,
                                              const float* __restrict__ w3d,
                                              float* __restrict__ out)
{
    __shared__ _Float16 t_lds[C_][64];   // 64 KiB
    __shared__ float    sred[8][64];

    // XCD-aware swizzle: each XCD gets a contiguous 128-block chunk (2 full b)
    const int bh = (blockIdx.x & 7) * 128 + (blockIdx.x >> 3);
    const int b  = bh >> 6;
    const int h  = bh & 63;
    const int tid = threadIdx.x;
    const int wl  = tid & 63;
    const int cg  = tid >> 6;
    const int c0  = cg * 64;
    const int bC  = b * C_;
    const int hw  = h * W_ + wl;

    const bool hvm = (h > 0), hvp = (h < H_ - 1);
    const bool wvm = (wl > 0), wvp = (wl < W_ - 1);

    const float* xb = x + (size_t)b * C_ * PLANE;

    float w3[27];
#pragma unroll
    for (int j = 0; j < 27; ++j) w3[j] = w3d[j];

    // wv[r] = h_out[b,r,h] * w_out[b,r,w]
    float4 wv[16];
    {
        const float4* Hp = (const float4*)(Hh + ((size_t)b * H_ + h) * R_);
        const float4* Wp = (const float4*)(Ww + ((size_t)b * W_ + wl) * R_);
#pragma unroll
        for (int r4 = 0; r4 < 16; ++r4) {
            float4 hv = Hp[r4];
            float4 wq = Wp[r4];
            wv[r4] = make_float4(hv.x * wq.x, hv.y * wq.y, hv.z * wq.z, hv.w * wq.w);
        }
    }

    float PA[9], PB[9], PC[9];
    ldplane(PA, xb, c0 - 1, hw, hvm, hvp, wvm, wvp);
    ldplane(PB, xb, c0,     hw, hvm, hvp, wvm, wvp);

    float Ssum = 0.f;
    int i = 0;
#pragma unroll 1
    for (int k = 0; k < 21; ++k) {       // 63 steps, rotation period 3
        STEP(PA, PB, PC);
        STEP(PB, PC, PA);
        STEP(PC, PA, PB);
    }
    STEP(PA, PB, PC);                    // step 64

    sred[cg][wl] = Ssum;
    __syncthreads();
    float Stot = 0.f;
#pragma unroll
    for (int g = 0; g < 8; ++g) Stot += sred[g][wl];
    const float rS = 1.f / Stot;

    const float* xp2 = xb + (size_t)c0 * PLANE + hw;
    float* op = out + (size_t)b * C_ * PLANE + (size_t)c0 * PLANE + hw;
#pragma unroll 4
    for (int i2 = 0; i2 < 64; ++i2) {
        const int c = c0 + i2;
        float t = (float)t_lds[c][wl];
        *op = fmaf(t, rS, *xp2);
        op  += PLANE;
        xp2 += PLANE;
    }
}

// ---------------------------------------------------------------------------
extern "C" void kernel_launch(void* const* d_in, const int* in_sizes, int n_in,
                              void* d_out, int out_size, void* d_ws, size_t ws_size,
                              hipStream_t stream)
{
    (void)in_sizes; (void)n_in; (void)out_size; (void)ws_size;
    const float* x   = (const float*)d_in[0];
    const float* w_c = (const float*)d_in[1];
    const float* a_c = (const float*)d_in[2];
    const float* w_w = (const float*)d_in[3];
    const float* a_w = (const float*)d_in[4];
    const float* w_h = (const float*)d_in[5];
    const float* a_h = (const float*)d_in[6];
    const float* w3d = (const float*)d_in[7];
    float* out = (float*)d_out;

    float* ws = (float*)d_ws;
    float* gc = ws;                         // B*C          = 8192
    float* pw = gc + B_ * C_;               // B*64*64      = 65536
    float* ph = pw + B_ * 64 * 64;          // B*64*64      = 65536
    float* Ar = ph + B_ * 64 * 64;          // B*C*R        = 524288
    float* Ww = Ar + (size_t)B_ * C_ * R_;  // B*W*R        = 65536
    float* Hh = Ww + (size_t)B_ * W_ * R_;  // B*H*R        = 65536

    k_part<<<B_ * 64, 256, 0, stream>>>(x, gc, pw, ph);
    k_finish<<<B_, 256, 0, stream>>>(gc, pw, ph,
                                     w_c, a_c, w_w, a_w, w_h, a_h,
                                     Ar, Ww, Hh);
    k_main<<<B_ * H_, 512, 0, stream>>>(x, Ar, Hh, Ww, w3d, out);
}

// Round 5
// 356.414 us; speedup vs baseline: 2.3904x; 1.5379x over previous
//
#include <hip/hip_runtime.h>
#include <hip/hip_bf16.h>

// Problem constants
#define B_  16
#define C_  512
#define H_  64
#define W_  64
#define R_  64
#define PLANE 4096
#define NPB 128           // partial-reduction blocks per batch (k_part grid = B*NPB)

typedef __attribute__((ext_vector_type(8))) short  bf16x8;
typedef __attribute__((ext_vector_type(4))) float  f32x4;

__device__ __forceinline__ unsigned short f2bf(float f) {
    __hip_bfloat16 h = __float2bfloat16(f);
    return *(unsigned short*)&h;
}
__device__ __forceinline__ float bf2f(unsigned short u) {
    __hip_bfloat16 h = *(__hip_bfloat16*)&u;
    return __bfloat162float(h);
}

// ---------------------------------------------------------------------------
// Stage 1: partial reductions, no atomics. Block = (b, group of 4 planes).
// grid = B*128, 256 threads. Thread owns w-cols 4*(tid&15)..+3, h-rows (tid>>4)+16k.
//   gc[b*512+c]  : exact plane sums (exclusive ownership)
//   pw[bid*64+w] : per-block gw partials
//   ph[bid*64+h] : per-block gh partials
// ---------------------------------------------------------------------------
__global__ __launch_bounds__(256) void k_part(const float* __restrict__ x,
                                              float* __restrict__ gc,
                                              float* __restrict__ pw,
                                              float* __restrict__ ph)
{
    const int bid = blockIdx.x;          // b*128 + blk
    const int b   = bid >> 7;
    const int blk = bid & 127;
    const int tid = threadIdx.x;

    const float4* xp = (const float4*)(x + ((size_t)b * C_ + (size_t)blk * 4) * PLANE);

    float4 gwacc = make_float4(0.f, 0.f, 0.f, 0.f);
    float  ghacc[4] = {0.f, 0.f, 0.f, 0.f};
    float  gcp[4];

#pragma unroll
    for (int p = 0; p < 4; ++p) {
        float psum = 0.f;
#pragma unroll
        for (int k = 0; k < 4; ++k) {
            float4 v = xp[p * 1024 + tid + 256 * k];
            gwacc.x += v.x; gwacc.y += v.y; gwacc.z += v.z; gwacc.w += v.w;
            float s = (v.x + v.y) + (v.z + v.w);
            ghacc[k] += s;
            psum += s;
        }
        // plane-sum butterfly over the wave
        psum += __shfl_xor(psum, 1, 64);
        psum += __shfl_xor(psum, 2, 64);
        psum += __shfl_xor(psum, 4, 64);
        psum += __shfl_xor(psum, 8, 64);
        psum += __shfl_xor(psum, 16, 64);
        psum += __shfl_xor(psum, 32, 64);
        gcp[p] = psum;
    }

    __shared__ float  gcs_s[4][4];
    __shared__ float4 wpart[16][17];
    __shared__ float  hpart[64][17];

    const int wv = tid >> 6;
    const int wl = tid & 63;
    if (wl == 0) {
#pragma unroll
        for (int p = 0; p < 4; ++p) gcs_s[wv][p] = gcp[p];
    }
    wpart[tid >> 4][tid & 15] = gwacc;
#pragma unroll
    for (int k = 0; k < 4; ++k) hpart[(tid >> 4) + 16 * k][tid & 15] = ghacc[k];
    __syncthreads();

    if (tid < 4) {
        gc[b * C_ + blk * 4 + tid] =
            gcs_s[0][tid] + gcs_s[1][tid] + gcs_s[2][tid] + gcs_s[3][tid];
    }
    if (tid < 16) {
        float4 s = make_float4(0.f, 0.f, 0.f, 0.f);
#pragma unroll
        for (int g = 0; g < 16; ++g) {
            float4 t = wpart[g][tid];
            s.x += t.x; s.y += t.y; s.z += t.z; s.w += t.w;
        }
        ((float4*)(pw + (size_t)bid * 64))[tid] = s;
    }
    if (tid < 64) {
        float s = 0.f;
#pragma unroll
        for (int j = 0; j < 16; ++j) s += hpart[tid][j];
        ph[(size_t)bid * 64 + tid] = s;
    }
}

// ---------------------------------------------------------------------------
// Stage 2: finish reductions + conv1d + PReLU. One block per b, 256 threads.
//   Abf[b][c][r] (bf16), Wwf[b][w][r] (f32), Hhf[b][h][r] (f32)
// ---------------------------------------------------------------------------
__global__ __launch_bounds__(256) void k_fin(const float* __restrict__ gc,
                                             const float* __restrict__ pw,
                                             const float* __restrict__ ph,
                                             const float* __restrict__ w_c,
                                             const float* __restrict__ a_c,
                                             const float* __restrict__ w_w,
                                             const float* __restrict__ a_w,
                                             const float* __restrict__ w_h,
                                             const float* __restrict__ a_h,
                                             unsigned short* __restrict__ Abf,
                                             float* __restrict__ Wwf,
                                             float* __restrict__ Hhf)
{
    const int b   = blockIdx.x;
    const int tid = threadIdx.x;
    const int w   = tid & 63;
    const int q   = tid >> 6;

    __shared__ float redw[4][65], redh[4][65];
    __shared__ float gws[64], ghs[64];
    __shared__ float gcs[C_ + 2];

    // each wave q reduces 32 of the 128 partial blocks of this b
    float sw = 0.f, sh = 0.f;
    const float* pwb = pw + ((size_t)b * NPB + q * 32) * 64 + w;
    const float* phb = ph + ((size_t)b * NPB + q * 32) * 64 + w;
#pragma unroll 8
    for (int j = 0; j < 32; ++j) {
        sw += pwb[j * 64];
        sh += phb[j * 64];
    }
    redw[q][w] = sw;
    redh[q][w] = sh;
    for (int i = tid; i < C_; i += 256) gcs[1 + i] = gc[b * C_ + i];
    if (tid == 0) { gcs[0] = 0.f; gcs[C_ + 1] = 0.f; }
    __syncthreads();
    if (tid < 64) {
        gws[tid] = redw[0][tid] + redw[1][tid] + redw[2][tid] + redw[3][tid];
        ghs[tid] = redh[0][tid] + redh[1][tid] + redh[2][tid] + redh[3][tid];
    }
    __syncthreads();

    const int r = tid & 63;
    // channel branch
    {
        const float k0 = w_c[r * 3], k1 = w_c[r * 3 + 1], k2 = w_c[r * 3 + 2];
        const float al = a_c[0];
        const float sc = 1.f / (float)PLANE;
        for (int jj = 0; jj < 128; ++jj) {
            const int c = (tid >> 6) + 4 * jj;
            float v = fmaf(gcs[c] * sc, k0,
                      fmaf(gcs[c + 1] * sc, k1, gcs[c + 2] * sc * k2));
            v = (v >= 0.f) ? v : al * v;
            Abf[((size_t)b * C_ + c) * R_ + r] = f2bf(v);
        }
    }
    // width branch
    {
        const float k0 = w_w[r * 3], k1 = w_w[r * 3 + 1], k2 = w_w[r * 3 + 2];
        const float al = a_w[0];
        const float sc = 1.f / (float)(C_ * H_);
        for (int jj = 0; jj < 16; ++jj) {
            const int wp = (tid >> 6) + 4 * jj;
            float g0 = (wp > 0)  ? gws[wp - 1] : 0.f;
            float g1 =             gws[wp];
            float g2 = (wp < 63) ? gws[wp + 1] : 0.f;
            float v = fmaf(g0 * sc, k0, fmaf(g1 * sc, k1, g2 * sc * k2));
            v = (v >= 0.f) ? v : al * v;
            Wwf[((size_t)b * W_ + wp) * R_ + r] = v;
        }
    }
    // height branch
    {
        const float k0 = w_h[r * 3], k1 = w_h[r * 3 + 1], k2 = w_h[r * 3 + 2];
        const float al = a_h[0];
        const float sc = 1.f / (float)(C_ * W_);
        for (int jj = 0; jj < 16; ++jj) {
            const int hp = (tid >> 6) + 4 * jj;
            float g0 = (hp > 0)  ? ghs[hp - 1] : 0.f;
            float g1 =             ghs[hp];
            float g2 = (hp < 63) ? ghs[hp + 1] : 0.f;
            float v = fmaf(g0 * sc, k0, fmaf(g1 * sc, k1, g2 * sc * k2));
            v = (v >= 0.f) ? v : al * v;
            Hhf[((size_t)b * H_ + hp) * R_ + r] = v;
        }
    }
}

// ---------------------------------------------------------------------------
// Stage 3: cp GEMM (MFMA bf16) + softmax over c, fully in-block.
// Block = (b,h), 256 threads = 4 waves; wave wv owns c-rows [wv*128, wv*128+128).
// Writes G = exp(cp)/S as bf16 into the first 128 B of each out row (b,c,h,:).
// ---------------------------------------------------------------------------
__global__ __launch_bounds__(256) void k_cp(const unsigned short* __restrict__ Abf,
                                            const float* __restrict__ Wwf,
                                            const float* __restrict__ Hhf,
                                            float* __restrict__ outbuf)
{
    __shared__ unsigned short cpb[C_][68];   // cp bf16 bits, padded
    __shared__ unsigned short btl[64][72];   // Bt[w][r] bf16, padded
    __shared__ float sred[4][64];
    __shared__ float sinv[64];

    const int bh = (blockIdx.x & 7) * 128 + (blockIdx.x >> 3);  // XCD swizzle
    const int b  = bh >> 6;
    const int h  = bh & 63;
    const int tid = threadIdx.x;

    // build Bt[w][r] = bf16( Ww[b,w,r] * Hh[b,h,r] )
    for (int i = tid; i < 4096; i += 256) {
        const int w = i >> 6, r = i & 63;
        float v = Wwf[((size_t)b * 64 + w) * 64 + r] * Hhf[((size_t)b * 64 + h) * 64 + r];
        btl[w][r] = f2bf(v);
    }
    __syncthreads();

    const int wv  = tid >> 6;
    const int l   = tid & 63;
    const int l15 = l & 15;
    const int lg  = l >> 4;

    // B fragments: lane l -> col w = nt*16+l15, k-chunk lg*8 (+kk*32)
    bf16x8 bfr[4][2];
#pragma unroll
    for (int nt = 0; nt < 4; ++nt)
#pragma unroll
        for (int kk = 0; kk < 2; ++kk)
            bfr[nt][kk] = *(const bf16x8*)&btl[nt * 16 + l15][kk * 32 + lg * 8];

    const unsigned short* Ab = Abf + ((size_t)b * C_ + wv * 128) * 64;
    float ssum[4] = {0.f, 0.f, 0.f, 0.f};

#pragma unroll
    for (int mt = 0; mt < 8; ++mt) {
        const unsigned short* ar = Ab + ((size_t)(mt * 16 + l15)) * 64 + lg * 8;
        bf16x8 a0 = *(const bf16x8*)ar;          // k 0..31 chunk
        bf16x8 a1 = *(const bf16x8*)(ar + 32);   // k 32..63 chunk
        f32x4 acc[4];
#pragma unroll
        for (int nt = 0; nt < 4; ++nt) {
            acc[nt] = (f32x4){0.f, 0.f, 0.f, 0.f};
            acc[nt] = __builtin_amdgcn_mfma_f32_16x16x32_bf16(a0, bfr[nt][0], acc[nt], 0, 0, 0);
            acc[nt] = __builtin_amdgcn_mfma_f32_16x16x32_bf16(a1, bfr[nt][1], acc[nt], 0, 0, 0);
        }
        // D layout: col(w) = l15 + nt*16, row(c) = mt*16 + lg*4 + reg
#pragma unroll
        for (int nt = 0; nt < 4; ++nt)
#pragma unroll
            for (int reg = 0; reg < 4; ++reg) {
                unsigned short ub = f2bf(acc[nt][reg]);
                float e = __expf(bf2f(ub));
                ssum[nt] += e;
                cpb[wv * 128 + mt * 16 + lg * 4 + reg][nt * 16 + l15] = ub;
            }
    }

    // reduce S over the 4 row-groups, then across waves
#pragma unroll
    for (int nt = 0; nt < 4; ++nt) {
        float s = ssum[nt];
        s += __shfl_xor(s, 16, 64);
        s += __shfl_xor(s, 32, 64);
        if (l < 16) sred[wv][nt * 16 + l] = s;
    }
    __syncthreads();
    if (tid < 64)
        sinv[tid] = 1.f / (sred[0][tid] + sred[1][tid] + sred[2][tid] + sred[3][tid]);
    __syncthreads();

    // normalize + write G bf16 into the head of each out row (b,c,h,:)
    float* ob = outbuf + (size_t)b * C_ * PLANE + h * 64;
    const float si = sinv[l];
#pragma unroll 4
    for (int i = 0; i < 128; ++i) {
        const int c = wv + 4 * i;
        float e = __expf(bf2f(cpb[c][l]));
        __hip_bfloat16* gp = (__hip_bfloat16*)(ob + (size_t)c * PLANE);
        gp[l] = __float2bfloat16(e * si);
    }
}

// ---------------------------------------------------------------------------
// Stage 4: streaming conv3d + out = res*G + x. Block = (b,h), 512 threads,
// no LDS; 3-plane lookahead pipeline, w-neighbors via shfl.
// ---------------------------------------------------------------------------
#define KSTEP(Pm, Pz, Pp, RVM, RV0, RVP, RG)                                     \
    do {                                                                         \
        float um = __shfl_up(RVM, 1, 64), dm = __shfl_down(RVM, 1, 64);          \
        float u0 = __shfl_up(RV0, 1, 64), d0 = __shfl_down(RV0, 1, 64);          \
        float up = __shfl_up(RVP, 1, 64), dp = __shfl_down(RVP, 1, 64);          \
        Pp[0] = wvm ? um : 0.f;  Pp[1] = RVM;  Pp[2] = wvp ? dm : 0.f;           \
        Pp[3] = wvm ? u0 : 0.f;  Pp[4] = RV0;  Pp[5] = wvp ? d0 : 0.f;           \
        Pp[6] = wvm ? up : 0.f;  Pp[7] = RVP;  Pp[8] = wvp ? dp : 0.f;           \
        const float gcur = RG;                                                   \
        {                                                                        \
            const int cc = c0 + i + 3;                                           \
            if (cc < C_) {                                                       \
                const float* xp = xb + (size_t)cc * PLANE + hw;                  \
                RVM = hvm ? xp[-64] : 0.f;                                       \
                RV0 = xp[0];                                                     \
                RVP = hvp ? xp[64] : 0.f;                                        \
            } else { RVM = 0.f; RV0 = 0.f; RVP = 0.f; }                          \
            const int cg2 = c0 + i + 2;                                          \
            RG = (cg2 < C_)                                                      \
               ? __bfloat162float(((const __hip_bfloat16*)(orow + (size_t)(i + 2) * PLANE))[wl]) \
               : 0.f;                                                            \
        }                                                                        \
        float ra = 0.f, rb = 0.f, rc = 0.f;                                      \
        _Pragma("unroll")                                                        \
        for (int j = 0; j < 9; ++j) {                                            \
            ra = fmaf(Pm[j], w3[j],      ra);                                    \
            rb = fmaf(Pz[j], w3[9 + j],  rb);                                    \
            rc = fmaf(Pp[j], w3[18 + j], rc);                                    \
        }                                                                        \
        orow[(size_t)i * PLANE + wl] = fmaf((ra + rb) + rc, gcur, Pz[4]);        \
        ++i;                                                                     \
    } while (0)

__global__ __launch_bounds__(512) void k_out(const float* __restrict__ x,
                                             const float* __restrict__ w3d,
                                             float* __restrict__ out)
{
    const int bh = (blockIdx.x & 7) * 128 + (blockIdx.x >> 3);  // XCD swizzle
    const int b  = bh >> 6;
    const int h  = bh & 63;
    const int tid = threadIdx.x;
    const int wl  = tid & 63;
    const int cg  = tid >> 6;
    const int c0  = cg * 64;
    const int hw  = h * W_ + wl;

    const bool hvm = (h > 0), hvp = (h < H_ - 1);
    const bool wvm = (wl > 0), wvp = (wl < W_ - 1);

    const float* xb = x + (size_t)b * C_ * PLANE;
    float* orow = out + ((size_t)b * C_ + c0) * PLANE + h * 64;

    float w3[27];
#pragma unroll
    for (int j = 0; j < 27; ++j) w3[j] = w3d[j];

    float PA[9], PB[9], PC[9];
    // prologue: PA = plane c0-1, PB = plane c0
    {
        float vm = 0.f, v0 = 0.f, vp = 0.f;
        if (c0 - 1 >= 0) {
            const float* xp = xb + (size_t)(c0 - 1) * PLANE + hw;
            vm = hvm ? xp[-64] : 0.f;  v0 = xp[0];  vp = hvp ? xp[64] : 0.f;
        }
        float um = __shfl_up(vm, 1, 64), dm = __shfl_down(vm, 1, 64);
        float u0 = __shfl_up(v0, 1, 64), d0 = __shfl_down(v0, 1, 64);
        float up = __shfl_up(vp, 1, 64), dp = __shfl_down(vp, 1, 64);
        PA[0] = wvm ? um : 0.f; PA[1] = vm; PA[2] = wvp ? dm : 0.f;
        PA[3] = wvm ? u0 : 0.f; PA[4] = v0; PA[5] = wvp ? d0 : 0.f;
        PA[6] = wvm ? up : 0.f; PA[7] = vp; PA[8] = wvp ? dp : 0.f;
    }
    {
        const float* xp = xb + (size_t)c0 * PLANE + hw;
        float vm = hvm ? xp[-64] : 0.f, v0 = xp[0], vp = hvp ? xp[64] : 0.f;
        float um = __shfl_up(vm, 1, 64), dm = __shfl_down(vm, 1, 64);
        float u0 = __shfl_up(v0, 1, 64), d0 = __shfl_down(v0, 1, 64);
        float up = __shfl_up(vp, 1, 64), dp = __shfl_down(vp, 1, 64);
        PB[0] = wvm ? um : 0.f; PB[1] = vm; PB[2] = wvp ? dm : 0.f;
        PB[3] = wvm ? u0 : 0.f; PB[4] = v0; PB[5] = wvp ? d0 : 0.f;
        PB[6] = wvm ? up : 0.f; PB[7] = vp; PB[8] = wvp ? dp : 0.f;
    }
    // raw prefetch: set0 = plane c0+1 & G[c0]; set1 = plane c0+2 & G[c0+1]
    float rvm0, rv00, rvp0, rg0, rvm1, rv01, rvp1, rg1;
    {
        const float* xp = xb + (size_t)(c0 + 1) * PLANE + hw;
        rvm0 = hvm ? xp[-64] : 0.f;  rv00 = xp[0];  rvp0 = hvp ? xp[64] : 0.f;
        rg0  = __bfloat162float(((const __hip_bfloat16*)orow)[wl]);
        const float* xq = xb + (size_t)(c0 + 2) * PLANE + hw;
        rvm1 = hvm ? xq[-64] : 0.f;  rv01 = xq[0];  rvp1 = hvp ? xq[64] : 0.f;
        rg1  = __bfloat162float(((const __hip_bfloat16*)(orow + PLANE))[wl]);
    }

    int i = 0;
#pragma unroll 1
    for (int k = 0; k < 10; ++k) {       // 60 steps
        KSTEP(PA, PB, PC, rvm0, rv00, rvp0, rg0);
        KSTEP(PB, PC, PA, rvm1, rv01, rvp1, rg1);
        KSTEP(PC, PA, PB, rvm0, rv00, rvp0, rg0);
        KSTEP(PA, PB, PC, rvm1, rv01, rvp1, rg1);
        KSTEP(PB, PC, PA, rvm0, rv00, rvp0, rg0);
        KSTEP(PC, PA, PB, rvm1, rv01, rvp1, rg1);
    }
    KSTEP(PA, PB, PC, rvm0, rv00, rvp0, rg0);   // 60
    KSTEP(PB, PC, PA, rvm1, rv01, rvp1, rg1);   // 61
    KSTEP(PC, PA, PB, rvm0, rv00, rvp0, rg0);   // 62
    KSTEP(PA, PB, PC, rvm1, rv01, rvp1, rg1);   // 63
}

// ---------------------------------------------------------------------------
extern "C" void kernel_launch(void* const* d_in, const int* in_sizes, int n_in,
                              void* d_out, int out_size, void* d_ws, size_t ws_size,
                              hipStream_t stream)
{
    (void)in_sizes; (void)n_in; (void)out_size; (void)ws_size;
    const float* x   = (const float*)d_in[0];
    const float* w_c = (const float*)d_in[1];
    const float* a_c = (const float*)d_in[2];
    const float* w_w = (const float*)d_in[3];
    const float* a_w = (const float*)d_in[4];
    const float* w_h = (const float*)d_in[5];
    const float* a_h = (const float*)d_in[6];
    const float* w3d = (const float*)d_in[7];
    float* out = (float*)d_out;

    float* ws = (float*)d_ws;
    float* gc  = ws;                              // 8192 floats
    float* pw  = gc + B_ * C_;                    // B*NPB*64 = 131072 floats
    float* ph  = pw + B_ * NPB * 64;              // 131072 floats
    unsigned short* Abf = (unsigned short*)(ph + B_ * NPB * 64);   // 1 MB bf16
    float* Wwf = (float*)(Abf + (size_t)B_ * C_ * R_);             // 65536 floats
    float* Hhf = Wwf + (size_t)B_ * W_ * R_;                       // 65536 floats
    // total ws ~= 2.63 MB (< proven 3.18 MB footprint)

    k_part<<<B_ * NPB, 256, 0, stream>>>(x, gc, pw, ph);
    k_fin<<<B_, 256, 0, stream>>>(gc, pw, ph,
                                  w_c, a_c, w_w, a_w, w_h, a_h,
                                  Abf, Wwf, Hhf);
    k_cp<<<B_ * H_, 256, 0, stream>>>(Abf, Wwf, Hhf, out);
    k_out<<<B_ * H_, 512, 0, stream>>>(x, w3d, out);
}